// Round 15
// baseline (29.840 us; speedup 1.0000x reference)
//
#include <hip/hip_runtime.h>

// FourierFilter2D: out[b,h,w,f] = Re( sum_c x[b,h,w,c] * W[c,h,w,f] ) + b_re[f]
// B=8, H=64, W=64, C=64, F=64. Output: [B][H][W][F] float32, REAL part only.
//
// r6-r14: 36.6 / 87 / 42 / 43.6 / 35.2 / 32.1 / 49.5 / 30.4 / 29.0 us.
// Rules: W exactly-once per block; dwordx4 (1KB/wave) streams; nt loads for
// single-use data; minimal LDS-broadcast instr count; conflict-free partials.
// r15 = r14 + (a) 2-deep W prefetch (8 fat loads in flight/wave steady-state;
// per-cp compute ~128cyc vs ~400-900cyc load latency needed deeper pipeline),
// (b) non-temporal x-stage loads (x is single-use too).
//
// Block = 4 waves x 4 hw; wave wid owns c-quarter [16wid,16wid+16) as 8 c-pairs.
// Grid 1024 blocks (4/CU, all co-resident). LDS 33.3KB. launch_bounds(256,4).

typedef float f32x2v __attribute__((ext_vector_type(2)));
typedef float f32x4v __attribute__((ext_vector_type(4)));

constexpr int Bb = 8;
constexpr int C  = 64;
constexpr int F  = 64;
constexpr int HW  = 4096;
constexpr int HWC = HW * C;         // 262144
constexpr int HWF = HW * F;         // 262144

__global__ __launch_bounds__(256, 4) void fourier_filter2d_kernel(
    const float* __restrict__ x_re, const float* __restrict__ x_im,
    const float* __restrict__ w_re, const float* __restrict__ w_im,
    const float* __restrict__ b_re,
    float* __restrict__ out)
{
    // Time-multiplexed LDS:
    //  phase A: f32x2 xs[(b*4+hl)*66 + c]            -> 2112 f32x2 = 16896 B
    //  phase B: float part[((b*4+wv)*4+hl)*65 + f]   -> 8319 floats = 33276 B
    __shared__ __align__(16) float smem[8320];
    f32x2v* xs = (f32x2v*)smem;

    const int t    = threadIdx.x;
    const int wid  = t >> 6;
    const int lane = t & 63;
    const int hw0  = blockIdx.x * 4;

    const float* __restrict__ wrb = w_re + (size_t)hw0 * F + lane * 4;
    const float* __restrict__ wib = w_im + (size_t)hw0 * F + lane * 4;
    const float bias = b_re[lane];

    const int c_base = wid * 16;

    // ---- 2-deep W prefetch: c-pairs cp=0,1 issued before the x-stage.
    f32x4v pre[2][4];   // [buf][wr0,wi0,wr1,wi1] — constant-indexed (SROA->regs)
    #pragma unroll
    for (int k = 0; k < 2; ++k) {
        const size_t o = (size_t)(c_base + 2 * k) * HWF;
        pre[k][0] = __builtin_nontemporal_load((const f32x4v*)(wrb + o));
        pre[k][1] = __builtin_nontemporal_load((const f32x4v*)(wib + o));
        pre[k][2] = __builtin_nontemporal_load((const f32x4v*)(wrb + o + HWF));
        pre[k][3] = __builtin_nontemporal_load((const f32x4v*)(wib + o + HWF));
    }

    // ---- Stage x for 4 hw (2048 f32x2). 2 chunks/thread, nt dwordx4 loads.
    #pragma unroll
    for (int k = 0; k < 2; ++k) {
        const int chunk = t + k * 256;        // b(8) x hl(4) x c4(16)
        const int b  = chunk >> 6;
        const int r  = chunk & 63;
        const int hl = r >> 4;
        const int c4 = (r & 15) * 4;
        const size_t g = (size_t)b * HWC + (size_t)(hw0 + hl) * C + c4;
        const f32x4v vr = __builtin_nontemporal_load((const f32x4v*)(x_re + g));
        const f32x4v vi = __builtin_nontemporal_load((const f32x4v*)(x_im + g));
        const int base = (b * 4 + hl) * 66 + c4;   // f32x2 units (even -> 16B ok)
        *(f32x4v*)&xs[base]     = (f32x4v){vr.x, vi.x, vr.y, vi.y};
        *(f32x4v*)&xs[base + 2] = (f32x4v){vr.z, vi.z, vr.w, vi.w};
    }
    __syncthreads();

    // ---- Compute: 8 c-pairs, 2-deep pipeline (copy -> prefetch -> FMA).
    const int hl = lane >> 4;            // lane's hw within block
    const int xbase0 = hl * 66;          // + b*264 + c (f32x2 units)

    f32x4v acc[Bb];
    #pragma unroll
    for (int b = 0; b < Bb; ++b) acc[b] = (f32x4v){0.f, 0.f, 0.f, 0.f};

    #pragma unroll
    for (int cp = 0; cp < 8; ++cp) {
        const f32x4v Wr0 = pre[cp & 1][0], Wi0 = pre[cp & 1][1];
        const f32x4v Wr1 = pre[cp & 1][2], Wi1 = pre[cp & 1][3];
        if (cp < 6) {
            const size_t o = (size_t)(c_base + 2 * (cp + 2)) * HWF;
            pre[cp & 1][0] = __builtin_nontemporal_load((const f32x4v*)(wrb + o));
            pre[cp & 1][1] = __builtin_nontemporal_load((const f32x4v*)(wib + o));
            pre[cp & 1][2] = __builtin_nontemporal_load((const f32x4v*)(wrb + o + HWF));
            pre[cp & 1][3] = __builtin_nontemporal_load((const f32x4v*)(wib + o + HWF));
        }
        const int c = c_base + cp * 2;
        #pragma unroll
        for (int b = 0; b < Bb; ++b) {
            // {xr(c), xi(c), xr(c+1), xi(c+1)} in one b128 (broadcast /16 lanes)
            const f32x4v xp = *(const f32x4v*)&xs[xbase0 + b * 264 + c];
            acc[b] = acc[b] + Wr0 * xp.x;
            acc[b] = acc[b] - Wi0 * xp.y;
            acc[b] = acc[b] + Wr1 * xp.z;
            acc[b] = acc[b] - Wi1 * xp.w;
        }
    }

    // ---- Cross-wave c-reduction, conflict-free partials (alias xs; fenced).
    __syncthreads();
    {
        const int q = lane & 15;
        #pragma unroll
        for (int b = 0; b < Bb; ++b) {
            const int rowbase = ((b * 4 + wid) * 4 + hl) * 65 + q * 4;
            #pragma unroll
            for (int j = 0; j < 4; ++j)
                smem[rowbase + j] = acc[b][j];   // banks (hl+4q)%32: 2/bank, free
        }
    }
    __syncthreads();

    // ---- Phase 2: wave wid -> hw = hw0+wid; lane -> f. Reads conflict-free.
    const int f = lane;
    #pragma unroll
    for (int b = 0; b < Bb; ++b) {
        const int rb = (b * 4) * 4 + wid;
        float s = (smem[(rb + 0) * 65 + f] + smem[(rb + 4) * 65 + f])
                + (smem[(rb + 8) * 65 + f] + smem[(rb + 12) * 65 + f]);
        __builtin_nontemporal_store(s + bias,
            out + (size_t)b * HWF + (size_t)(hw0 + wid) * F + f);
    }
}

extern "C" void kernel_launch(void* const* d_in, const int* in_sizes, int n_in,
                              void* d_out, int out_size, void* d_ws, size_t ws_size,
                              hipStream_t stream) {
    const float* x_re = (const float*)d_in[0];
    const float* x_im = (const float*)d_in[1];
    const float* w_re = (const float*)d_in[2];
    const float* w_im = (const float*)d_in[3];
    const float* b_re = (const float*)d_in[4];
    float* out = (float*)d_out;

    const int blocks = HW / 4; // 1024 blocks x 4 waves, all co-resident
    fourier_filter2d_kernel<<<blocks, 256, 0, stream>>>(
        x_re, x_im, w_re, w_im, b_re, out);
}

// Round 16
// 28.411 us; speedup vs baseline: 1.0503x; 1.0503x over previous
//
#include <hip/hip_runtime.h>

// FourierFilter2D: out[b,h,w,f] = Re( sum_c x[b,h,w,c] * W[c,h,w,f] ) + b_re[f]
// B=8, H=64, W=64, C=64, F=64. Output: [B][H][W][F] float32, REAL part only.
//
// r6-r15: 36.6 / 87 / 42 / 43.6 / 35.2 / 32.1 / 49.5 / 30.4 / 29.0 / 29.8 us.
// This is r14 RESTORED (measured best, 29.0us): r15's 2-deep prefetch + nt
// x-stage regressed (+0.8us) -> deeper source pipelining is null here
// (consistent with m131-m140: compiler scheduling already near-optimal).
//
// Established rules (each A/B-tested in r6-r15):
//  - W fetched EXACTLY once per block (r12: 8x dup -> 49.5us).
//  - dwordx4 1KB/wave W streams (r11 vs r10: fat loads >> occupancy).
//  - nt W loads (single-use stream; keeps x/out L2/L3-resident): r13 -1.7us.
//  - 1-deep W prefetch issued BEFORE x-stage (r14 -1.4us).
//  - conflict-free partials: ((b*4+wv)*4+hl)*65 + q*4+j (writes 2/bank,
//    reads 2/bank, both free).
// Roofline: 159.4MB compulsory -> 25.3us @6.3TB/s; 29.0 incl. launch
// overhead + mixed-stream efficiency ~= practical floor.
//
// Block = 4 waves x 4 hw; wave wid owns c-quarter [16wid,16wid+16) as 8 c-pairs.
// Grid 1024 blocks (4/CU, all co-resident). LDS 33.3KB. launch_bounds(256,4).

typedef float f32x2v __attribute__((ext_vector_type(2)));
typedef float f32x4v __attribute__((ext_vector_type(4)));

constexpr int Bb = 8;
constexpr int C  = 64;
constexpr int F  = 64;
constexpr int HW  = 4096;
constexpr int HWC = HW * C;         // 262144
constexpr int HWF = HW * F;         // 262144

__global__ __launch_bounds__(256, 4) void fourier_filter2d_kernel(
    const float* __restrict__ x_re, const float* __restrict__ x_im,
    const float* __restrict__ w_re, const float* __restrict__ w_im,
    const float* __restrict__ b_re,
    float* __restrict__ out)
{
    // Time-multiplexed LDS:
    //  phase A: f32x2 xs[(b*4+hl)*66 + c]            -> 2112 f32x2 = 16896 B
    //  phase B: float part[((b*4+wv)*4+hl)*65 + f]   -> 8319 floats = 33276 B
    __shared__ __align__(16) float smem[8320];
    f32x2v* xs = (f32x2v*)smem;

    const int t    = threadIdx.x;
    const int wid  = t >> 6;
    const int lane = t & 63;
    const int hw0  = blockIdx.x * 4;

    const float* __restrict__ wrb = w_re + (size_t)hw0 * F + lane * 4;
    const float* __restrict__ wib = w_im + (size_t)hw0 * F + lane * 4;
    const float bias = b_re[lane];

    // ---- W prefetch for cp=0 (before x-stage: stream starts immediately).
    const int c_base = wid * 16;
    size_t o0 = (size_t)c_base * HWF;
    f32x4v nWr0 = __builtin_nontemporal_load((const f32x4v*)(wrb + o0));
    f32x4v nWi0 = __builtin_nontemporal_load((const f32x4v*)(wib + o0));
    f32x4v nWr1 = __builtin_nontemporal_load((const f32x4v*)(wrb + o0 + HWF));
    f32x4v nWi1 = __builtin_nontemporal_load((const f32x4v*)(wib + o0 + HWF));

    // ---- Stage x for 4 hw (2048 f32x2). 2 chunks/thread, dwordx4 loads.
    #pragma unroll
    for (int k = 0; k < 2; ++k) {
        const int chunk = t + k * 256;        // b(8) x hl(4) x c4(16)
        const int b  = chunk >> 6;
        const int r  = chunk & 63;
        const int hl = r >> 4;
        const int c4 = (r & 15) * 4;
        const size_t g = (size_t)b * HWC + (size_t)(hw0 + hl) * C + c4;
        const f32x4v vr = *(const f32x4v*)(x_re + g);
        const f32x4v vi = *(const f32x4v*)(x_im + g);
        const int base = (b * 4 + hl) * 66 + c4;   // f32x2 units (even -> 16B ok)
        *(f32x4v*)&xs[base]     = (f32x4v){vr.x, vi.x, vr.y, vi.y};
        *(f32x4v*)&xs[base + 2] = (f32x4v){vr.z, vi.z, vr.w, vi.w};
    }
    __syncthreads();

    // ---- Compute: 8 c-pairs, 1-deep W prefetch pipeline.
    const int hl = lane >> 4;            // lane's hw within block
    const int xbase0 = hl * 66;          // + b*264 + c (f32x2 units)

    f32x4v acc[Bb];
    #pragma unroll
    for (int b = 0; b < Bb; ++b) acc[b] = (f32x4v){0.f, 0.f, 0.f, 0.f};

    #pragma unroll
    for (int cp = 0; cp < 8; ++cp) {
        const f32x4v Wr0 = nWr0, Wi0 = nWi0, Wr1 = nWr1, Wi1 = nWi1;
        if (cp < 7) {
            const size_t o = (size_t)(c_base + (cp + 1) * 2) * HWF;
            nWr0 = __builtin_nontemporal_load((const f32x4v*)(wrb + o));
            nWi0 = __builtin_nontemporal_load((const f32x4v*)(wib + o));
            nWr1 = __builtin_nontemporal_load((const f32x4v*)(wrb + o + HWF));
            nWi1 = __builtin_nontemporal_load((const f32x4v*)(wib + o + HWF));
        }
        const int c = c_base + cp * 2;
        #pragma unroll
        for (int b = 0; b < Bb; ++b) {
            // {xr(c), xi(c), xr(c+1), xi(c+1)} in one b128 (broadcast /16 lanes)
            const f32x4v xp = *(const f32x4v*)&xs[xbase0 + b * 264 + c];
            acc[b] = acc[b] + Wr0 * xp.x;
            acc[b] = acc[b] - Wi0 * xp.y;
            acc[b] = acc[b] + Wr1 * xp.z;
            acc[b] = acc[b] - Wi1 * xp.w;
        }
    }

    // ---- Cross-wave c-reduction, conflict-free partials (alias xs; fenced).
    __syncthreads();
    {
        const int q = lane & 15;
        #pragma unroll
        for (int b = 0; b < Bb; ++b) {
            const int rowbase = ((b * 4 + wid) * 4 + hl) * 65 + q * 4;
            #pragma unroll
            for (int j = 0; j < 4; ++j)
                smem[rowbase + j] = acc[b][j];   // banks (hl+4q)%32: 2/bank, free
        }
    }
    __syncthreads();

    // ---- Phase 2: wave wid -> hw = hw0+wid; lane -> f. Reads conflict-free.
    const int f = lane;
    #pragma unroll
    for (int b = 0; b < Bb; ++b) {
        const int rb = (b * 4) * 4 + wid;
        float s = (smem[(rb + 0) * 65 + f] + smem[(rb + 4) * 65 + f])
                + (smem[(rb + 8) * 65 + f] + smem[(rb + 12) * 65 + f]);
        __builtin_nontemporal_store(s + bias,
            out + (size_t)b * HWF + (size_t)(hw0 + wid) * F + f);
    }
}

extern "C" void kernel_launch(void* const* d_in, const int* in_sizes, int n_in,
                              void* d_out, int out_size, void* d_ws, size_t ws_size,
                              hipStream_t stream) {
    const float* x_re = (const float*)d_in[0];
    const float* x_im = (const float*)d_in[1];
    const float* w_re = (const float*)d_in[2];
    const float* w_im = (const float*)d_in[3];
    const float* b_re = (const float*)d_in[4];
    float* out = (float*)d_out;

    const int blocks = HW / 4; // 1024 blocks x 4 waves, all co-resident
    fourier_filter2d_kernel<<<blocks, 256, 0, stream>>>(
        x_re, x_im, w_re, w_im, b_re, out);
}